// Round 10
// baseline (203.574 us; speedup 1.0000x reference)
//
#include <hip/hip_runtime.h>

// VQ-VAE vector quantization, MI355X gfx950.
// B=16, C=64, H=W=64 -> N=65536 pixels; K=1024 codes, dim 64.
// NUMERICS (DO NOT CHANGE — r7 passed absmax 0.0 with exactly this):
//   nz/ne: numpy pairwise sum, 8-accumulator unroll, products rounded
//          separately (no fma contraction);
//   dot:   single ascending fp32 fma chain per (pixel,code);
//   d = fl( fl(nz - fl(2*dot)) + ne ); strict-< ascending-k tie-break.
//   ~135 pixels are decided by quantized ties.
//
// Perf history:
//   r7 161 | r8 185 | r9 137 | r12 242 | r13 137 | r14 1244 | r15 135
//   r16 hybrid LDS+SGPR argmin 133, total 196 (BEST).
//   r17 KCHUNK=256 + FB=128 finalize: 209 (finalize grid is pixel-bound:
//       65536 threads = 4 waves/CU at ANY block size).
//   r18 4-way channel split w/ LDS+sync: 218 (confounded: phases+sync).
//   r19 LDS/SMEM rebalance: conflicts->0, VALUBusy 83%, dur FLAT 138 —
//       7th flat argmin variant. Serial-chain lock puts dot FMAs at
//       ~83 µs (103 TF m07 ceiling); argmin ~138 is ~common-sense floor.
//       ARGMIN CLOSED: r16 verbatim below.
// r20: finalize TLP fix, minimal form — 2 threads/pixel (32 ch each),
//   NO phases/LDS/sync: both half-threads duplicate the cheap chunk-reduce
//   (4 VMEM + 8 compares, exact r16 ascending strict-<). Wave-half layout:
//   lanes 0-31 = 32 px ch0-31, lanes 32-63 = same px ch32-63 -> every
//   z/zq access = 2x128B contiguous segments. 2048 waves = 8 waves/CU,
//   VMEM/thread 208 -> ~77. Loss 32-ch chains (r17/r18 bit-validated
//   grouping envelope).
#define N_PIX   65536
#define CDIM    64
#define KCODES  1024
#define HWSZ    4096          // H*W
#define KCHUNK  128           // codes per argmin block
#define NCHUNK  8             // KCODES / KCHUNK
#define TPB     256
#define PXT     2             // pixels per thread; 128*256*2 == N_PIX exactly
#define GRIDX   (N_PIX / (TPB * PXT))   // 128
#define FPPB    128           // finalize pixels per block (256 thr, 2 thr/px)

// workspace layout (float-element offsets) — r16 layout
#define OFF_CTR  0            // 1 u32: finalize done-counter
#define OFF_MIN  1024         // 65536*8 f32: per-chunk min score
#define OFF_IDX  525312       // 65536*8 i32: per-chunk argmin
#define OFF_LOSS 1049600      // 1 f32: SSE accumulator

// output layout (float-element offsets): z_q | indices | loss
#define OUT_IDX  (N_PIX * CDIM)         // 4194304
#define OUT_LOSS (OUT_IDX + N_PIX)      // 4259840

typedef __attribute__((ext_vector_type(16))) float f32x16;

// exact numpy pairwise ||.||^2 for pixel registers — EXACT r9-verified form.
__device__ __forceinline__ float np_nz(const float* zr) {
    float r0 = zr[0]*zr[0], r1 = zr[1]*zr[1], r2 = zr[2]*zr[2], r3 = zr[3]*zr[3];
    float r4 = zr[4]*zr[4], r5 = zr[5]*zr[5], r6 = zr[6]*zr[6], r7 = zr[7]*zr[7];
#pragma unroll
    for (int i = 8; i < CDIM; i += 8) {
        r0 = r0 + zr[i+0]*zr[i+0]; r1 = r1 + zr[i+1]*zr[i+1];
        r2 = r2 + zr[i+2]*zr[i+2]; r3 = r3 + zr[i+3]*zr[i+3];
        r4 = r4 + zr[i+4]*zr[i+4]; r5 = r5 + zr[i+5]*zr[i+5];
        r6 = r6 + zr[i+6]*zr[i+6]; r7 = r7 + zr[i+7]*zr[i+7];
    }
    return ((r0 + r1) + (r2 + r3)) + ((r4 + r5) + (r6 + r7));
}

// ---------------- Kernel A: split-K argmin, hybrid LDS+SGPR (r16 verbatim) --
// grid = (GRIDX, NCHUNK); block = TPB.
__global__ __launch_bounds__(TPB, 3) void vq_argmin(const float* __restrict__ z,
                                                    const float* __restrict__ emb,
                                                    float* __restrict__ cmin,
                                                    int* __restrict__ cidx,
                                                    float* __restrict__ ws) {
#pragma clang fp contract(off)
    __shared__ float se[KCHUNK * CDIM];   // 32 KB
    __shared__ float sn[KCHUNK];

    const int chunk = blockIdx.y;
    const int k0 = chunk * KCHUNK;

    if ((blockIdx.x | blockIdx.y) == 0 && threadIdx.x == 0) {
        ws[OFF_LOSS] = 0.0f;                       // stream-ordered before finalize
        ((unsigned*)ws)[OFF_CTR] = 0u;             // graph-replay / re-poison safe
    }

    // stage this chunk's embedding rows (coalesced float4)
    const float4* esrc = (const float4*)(emb + (size_t)k0 * CDIM);
    float4* edst = (float4*)se;
    for (int i = threadIdx.x; i < KCHUNK * CDIM / 4; i += TPB) edst[i] = esrc[i];
    __syncthreads();
    // fused prep: ||e_k||^2 from the bit-exact staged copy (validated r12-r16).
    // Known cost: 32-way bank conflict here, ~2M cycles (~3 µs). Accepted.
    if (threadIdx.x < KCHUNK) {
        const float* e = se + threadIdx.x * CDIM;
        float r0 = e[0]*e[0], r1 = e[1]*e[1], r2 = e[2]*e[2], r3 = e[3]*e[3];
        float r4 = e[4]*e[4], r5 = e[5]*e[5], r6 = e[6]*e[6], r7 = e[7]*e[7];
#pragma unroll
        for (int i = 8; i < CDIM; i += 8) {
            r0 = r0 + e[i+0]*e[i+0]; r1 = r1 + e[i+1]*e[i+1];
            r2 = r2 + e[i+2]*e[i+2]; r3 = r3 + e[i+3]*e[i+3];
            r4 = r4 + e[i+4]*e[i+4]; r5 = r5 + e[i+5]*e[i+5];
            r6 = r6 + e[i+6]*e[i+6]; r7 = r7 + e[i+7]*e[i+7];
        }
        sn[threadIdx.x] = ((r0 + r1) + (r2 + r3)) + ((r4 + r5) + (r6 + r7));
    }
    __syncthreads();

    // two pixels per thread, lane-coalesced; no tail (128*256*2 == N_PIX)
    const int p0 = blockIdx.x * (TPB * PXT) + threadIdx.x;
    const int p1 = p0 + TPB;

    float zr0[CDIM], zr1[CDIM];
    {
        const int b0  = p0 >> 12, hw0 = p0 & (HWSZ - 1);
        const int b1  = p1 >> 12, hw1 = p1 & (HWSZ - 1);
        const float* zp0 = z + ((size_t)(b0 * CDIM) << 12) + hw0;
        const float* zp1 = z + ((size_t)(b1 * CDIM) << 12) + hw1;
#pragma unroll
        for (int c = 0; c < CDIM; ++c) {
            zr0[c] = zp0[(size_t)c << 12];
            zr1[c] = zp1[(size_t)c << 12];
        }
    }
    const float nz0 = np_nz(zr0);
    const float nz1 = np_nz(zr1);

    float best0 = 3.4e38f, best1 = 3.4e38f;
    int   bi0   = k0,      bi1   = k0;

    for (int kk = 0; kk < KCHUNK; kk += 2) {
        // --- issue SGPR stream for code kk+1 (erow + 0x100..0x1c0) ---------
        const float* erow = emb + (size_t)(k0 + kk) * CDIM;
        f32x16 ec0, ec1, ec2, ec3;
        asm volatile(
            "s_load_dwordx16 %0, %4, 0x100\n\t"
            "s_load_dwordx16 %1, %4, 0x140\n\t"
            "s_load_dwordx16 %2, %4, 0x180\n\t"
            "s_load_dwordx16 %3, %4, 0x1c0"
            : "=s"(ec0), "=s"(ec1), "=s"(ec2), "=s"(ec3)
            : "s"(erow));

        // --- LDS phase: code kk for both pixels (r9's exact chains) --------
        const float4* e0 = (const float4*)(se + kk * CDIM);
        float a00 = 0.f, a01 = 0.f, a10 = 0.f, a11 = 0.f;
#pragma unroll
        for (int j = 0; j < 16; ++j) {
            float4 v0 = e0[j];                 // uniform addr -> LDS broadcast
            a00 = fmaf(zr0[4*j+0], v0.x, a00);
            a00 = fmaf(zr0[4*j+1], v0.y, a00);
            a00 = fmaf(zr0[4*j+2], v0.z, a00);
            a00 = fmaf(zr0[4*j+3], v0.w, a00);
            a10 = fmaf(zr1[4*j+0], v0.x, a10);
            a10 = fmaf(zr1[4*j+1], v0.y, a10);
            a10 = fmaf(zr1[4*j+2], v0.z, a10);
            a10 = fmaf(zr1[4*j+3], v0.w, a10);
        }

        // --- wait: pinned AFTER the LDS phase (produces a00,a10) and BEFORE
        //     the SGPR phase (consumes ec0..ec3 as this asm's outputs) -------
        asm volatile("s_waitcnt lgkmcnt(0)"
                     : "+s"(ec0), "+s"(ec1), "+s"(ec2), "+s"(ec3),
                       "+v"(a00), "+v"(a10));

        // --- SGPR phase: code kk+1 for both pixels (r15's exact chains) ----
#pragma unroll
        for (int j = 0; j < 16; ++j) {
            a01 = fmaf(zr0[j], ec0[j], a01);   // v_fma: VGPR,SGPR,VGPR
            a11 = fmaf(zr1[j], ec0[j], a11);
        }
#pragma unroll
        for (int j = 0; j < 16; ++j) {
            a01 = fmaf(zr0[16+j], ec1[j], a01);
            a11 = fmaf(zr1[16+j], ec1[j], a11);
        }
#pragma unroll
        for (int j = 0; j < 16; ++j) {
            a01 = fmaf(zr0[32+j], ec2[j], a01);
            a11 = fmaf(zr1[32+j], ec2[j], a11);
        }
#pragma unroll
        for (int j = 0; j < 16; ++j) {
            a01 = fmaf(zr0[48+j], ec3[j], a01);
            a11 = fmaf(zr1[48+j], ec3[j], a11);
        }

        // d and argmin — exact r9 expression shapes and update order
        float d00 = (nz0 - 2.0f * a00) + sn[kk];
        float d01 = (nz0 - 2.0f * a01) + sn[kk + 1];
        float d10 = (nz1 - 2.0f * a10) + sn[kk];
        float d11 = (nz1 - 2.0f * a11) + sn[kk + 1];
        if (d00 < best0) { best0 = d00; bi0 = k0 + kk; }
        if (d01 < best0) { best0 = d01; bi0 = k0 + kk + 1; }
        if (d10 < best1) { best1 = d10; bi1 = k0 + kk; }
        if (d11 < best1) { best1 = d11; bi1 = k0 + kk + 1; }
    }
    cmin[(p0 << 3) + chunk] = best0;
    cidx[(p0 << 3) + chunk] = bi0;
    cmin[(p1 << 3) + chunk] = best1;
    cidx[(p1 << 3) + chunk] = bi1;
}

// ---------------- Kernel B: reduce chunks, gather z_q, loss + emit ----------
// 2 threads per pixel, 32 channels each; no LDS handoff, no phases.
// Wave layout: lane&31 selects pixel, lane>>5 selects channel half ->
// every z/zq instruction touches two 128B contiguous segments.
// grid = N_PIX/FPPB = 512 blocks -> 2048 waves = 8 waves/CU (2x r16 TLP).
__global__ __launch_bounds__(TPB) void vq_finalize(const float* __restrict__ z,
                                                   const float* __restrict__ emb,
                                                   const float* __restrict__ cmin,
                                                   const int* __restrict__ cidx,
                                                   float* __restrict__ out,
                                                   float* __restrict__ ws) {
    const int lane = threadIdx.x & 63;
    const int wave = threadIdx.x >> 6;                  // 0..3
    const int p    = blockIdx.x * FPPB + (wave << 5) + (lane & 31);
    const int h    = lane >> 5;                         // channel half 0/1

    // chunk-reduce, duplicated in both half-threads (4 VMEM + 8 compares);
    // ascending strict < keeps the earliest (lowest-k) minimum — r16 order.
    const float4* cmv = (const float4*)(cmin + ((size_t)p << 3));
    const int4*   civ = (const int4*)(cidx + ((size_t)p << 3));
    float4 cm0 = cmv[0], cm1 = cmv[1];
    int4   ci0 = civ[0], ci1 = civ[1];
    float best = cm0.x;  int bi = ci0.x;
    if (cm0.y < best) { best = cm0.y; bi = ci0.y; }
    if (cm0.z < best) { best = cm0.z; bi = ci0.z; }
    if (cm0.w < best) { best = cm0.w; bi = ci0.w; }
    if (cm1.x < best) { best = cm1.x; bi = ci1.x; }
    if (cm1.y < best) { best = cm1.y; bi = ci1.y; }
    if (cm1.z < best) { best = cm1.z; bi = ci1.z; }
    if (cm1.w < best) { best = cm1.w; bi = ci1.w; }

    if (h == 0) out[OUT_IDX + p] = (float)bi;   // lanes 0-31: 128B contiguous

    // this half's 32 channels of the winning row: 8 float4 (scattered by bi)
    float e[32];
    {
        const float4* ev = (const float4*)(emb + (size_t)bi * CDIM + (h << 5));
#pragma unroll
        for (int j = 0; j < 8; ++j) {
            float4 v = ev[j];
            e[4*j+0] = v.x; e[4*j+1] = v.y; e[4*j+2] = v.z; e[4*j+3] = v.w;
        }
    }

    const int b  = p >> 12;
    const int hw = p & (HWSZ - 1);
    const int c0 = h << 5;                      // 0 or 32
    const float* zp = z   + ((size_t)(b * CDIM + c0) << 12) + hw;
    float*       zq = out + ((size_t)(b * CDIM + c0) << 12) + hw;

    float ls = 0.0f;
#pragma unroll
    for (int j = 0; j < 32; ++j) {
        float zv = zp[(size_t)j << 12];         // 2x128B coalesced
        float d = e[j] - zv;                    // identical per-element math
        ls = fmaf(d, d, ls);
        zq[(size_t)j << 12] = e[j];             // 2x128B coalesced
    }

    // wave reduce (sums both halves of 32 pixels) -> block -> one atomic
#pragma unroll
    for (int off = 32; off > 0; off >>= 1) ls += __shfl_down(ls, off);
    __shared__ float wsum[TPB / 64];
    if (lane == 0) wsum[wave] = ls;
    __syncthreads();
    if (threadIdx.x == 0) {
        float s = (wsum[0] + wsum[1]) + (wsum[2] + wsum[3]);
        float* loss_acc = ws + OFF_LOSS;
        atomicAdd(loss_acc, s);
        __threadfence();                               // add visible before count
        unsigned* ctr = (unsigned*)ws + OFF_CTR;
        unsigned old = atomicAdd(ctr, 1u);
        if (old == (unsigned)(gridDim.x - 1)) {        // last block: all adds done
            __threadfence();
            float total = atomicAdd(loss_acc, 0.0f);   // coherent L2 read
            // vq_loss + beta*commitment = (1+0.25) * SSE / numel(z)
            out[OUT_LOSS] = total * (1.25f / (float)(N_PIX * CDIM));
        }
    }
}

extern "C" void kernel_launch(void* const* d_in, const int* in_sizes, int n_in,
                              void* d_out, int out_size, void* d_ws, size_t ws_size,
                              hipStream_t stream) {
    const float* z   = (const float*)d_in[0];
    const float* emb = (const float*)d_in[1];
    float* ws   = (float*)d_ws;
    float* out  = (float*)d_out;
    float* cmin = ws + OFF_MIN;
    int*   cidx = (int*)(ws + OFF_IDX);

    vq_argmin<<<dim3(GRIDX, NCHUNK), dim3(TPB), 0, stream>>>(z, emb, cmin, cidx, ws);
    vq_finalize<<<dim3(N_PIX / FPPB), dim3(TPB), 0, stream>>>(z, emb, cmin, cidx, out, ws);
}